// Round 6
// baseline (23984.334 us; speedup 1.0000x reference)
//
#include <hip/hip_runtime.h>
#include <hip/hip_bf16.h>

#define SEQ   4096
#define HID   512
#define GDIM  2048           // 4*HID
#define NSCAN 64             // scan participants (one XCD: 32 CUs x 2 WGs)
#define GRID_SCAN 512        // oversubscribe so some XCD surely fills 64 WGs
#define SPIN_CAP 4096        // fast-path bound before sticky fallback

// ---------------- workspace layout (bytes) ----------------
// [0, 33554432)        : gx  [SEQ][GDIM] f32  (32 MB)
// [+0, +16384)         : hpF [2][512] 16B slots, sc0/L2 fast buffer
//                        slot s words: {epoch16<<16|f16(h_2s)},{epoch16<<16|f16(h_2s+1)}
// [+16384, +32768)     : hpS [2][512] 16B slots, agent/MALL mirror (fallback)
// [+32768, +32808)     : election: xcnt[8], winlock, winner
#define GX_BYTES   (33554432L)
#define INIT_WORDS 8202      // (32768 + 40)/4

typedef unsigned uint;
typedef uint  v4u __attribute__((ext_vector_type(4)));
typedef uint  v2u __attribute__((ext_vector_type(2)));
typedef _Float16 half2v __attribute__((ext_vector_type(2)));

static __device__ __forceinline__ half2v pack_f16(float a, float b) {
    return __builtin_bit_cast(half2v, __builtin_amdgcn_cvt_pkrtz(a, b));
}

#if __has_builtin(__builtin_amdgcn_fdot2)
#define FDOT2(a,b,c) __builtin_amdgcn_fdot2((a),(b),(c),false)
#else
static __device__ __forceinline__ float FDOT2(half2v a, half2v b, float c) {
    return c + (float)a.x * (float)b.x + (float)a.y * (float)b.y;
}
#endif

// =========================================================
// Kernel A: gx[t][j] = emb[tok[t]] . W_ih[j] + b_ih[j] + b_hh[j]
// (unchanged from the verified kernel)
// =========================================================
__global__ __launch_bounds__(256) void gemm_gx(
    const int*   __restrict__ tokens,
    const float* __restrict__ emb,
    const float* __restrict__ W_ih,
    const float* __restrict__ b_ih,
    const float* __restrict__ b_hh,
    float*       __restrict__ gx,
    int*         __restrict__ initzone)
{
    __shared__ float As[64][33];
    __shared__ float Bs[64][33];
    __shared__ int   tok_s[64];

    const int tid = threadIdx.x;
    const int j0  = blockIdx.x * 64;
    const int t0  = blockIdx.y * 64;

    if (blockIdx.x == 0 && blockIdx.y == 0) {
        for (int i = tid; i < INIT_WORDS; i += 256) initzone[i] = 0;
    }
    if (tid < 64) tok_s[tid] = tokens[t0 + tid];
    __syncthreads();

    const int i  = tid >> 2;
    const int ko = (tid & 3) * 8;
    const int ty = tid >> 4;
    const int tx = tid & 15;

    const long arow = (long)tok_s[i] * HID;
    const long brow = (long)(j0 + i) * HID;

    float acc[4][4] = {};

    for (int k0 = 0; k0 < HID; k0 += 32) {
        float4 a0 = *(const float4*)&emb[arow + k0 + ko];
        float4 a1 = *(const float4*)&emb[arow + k0 + ko + 4];
        float4 b0 = *(const float4*)&W_ih[brow + k0 + ko];
        float4 b1 = *(const float4*)&W_ih[brow + k0 + ko + 4];
        As[i][ko+0]=a0.x; As[i][ko+1]=a0.y; As[i][ko+2]=a0.z; As[i][ko+3]=a0.w;
        As[i][ko+4]=a1.x; As[i][ko+5]=a1.y; As[i][ko+6]=a1.z; As[i][ko+7]=a1.w;
        Bs[i][ko+0]=b0.x; Bs[i][ko+1]=b0.y; Bs[i][ko+2]=b0.z; Bs[i][ko+3]=b0.w;
        Bs[i][ko+4]=b1.x; Bs[i][ko+5]=b1.y; Bs[i][ko+6]=b1.z; Bs[i][ko+7]=b1.w;
        __syncthreads();

        #pragma unroll
        for (int kk = 0; kk < 32; ++kk) {
            float av0 = As[ty*4+0][kk], av1 = As[ty*4+1][kk];
            float av2 = As[ty*4+2][kk], av3 = As[ty*4+3][kk];
            float bv0 = Bs[tx*4+0][kk], bv1 = Bs[tx*4+1][kk];
            float bv2 = Bs[tx*4+2][kk], bv3 = Bs[tx*4+3][kk];
            acc[0][0] += av0*bv0; acc[0][1] += av0*bv1; acc[0][2] += av0*bv2; acc[0][3] += av0*bv3;
            acc[1][0] += av1*bv0; acc[1][1] += av1*bv1; acc[1][2] += av1*bv2; acc[1][3] += av1*bv3;
            acc[2][0] += av2*bv0; acc[2][1] += av2*bv1; acc[2][2] += av2*bv2; acc[2][3] += av2*bv3;
            acc[3][0] += av3*bv0; acc[3][1] += av3*bv1; acc[3][2] += av3*bv2; acc[3][3] += av3*bv3;
        }
        __syncthreads();
    }

    #pragma unroll
    for (int m = 0; m < 4; ++m) {
        const long t = t0 + ty*4 + m;
        #pragma unroll
        for (int n = 0; n < 4; ++n) {
            const int j = j0 + tx*4 + n;
            gx[t*GDIM + j] = acc[m][n] + b_ih[j] + b_hh[j];
        }
    }
}

// =========================================================
// Kernel B: round-5 structure (single {epoch16|f16}-dword detect) with
// the broadcast moved to XCD-L2 scope:
//  - publish: sc0 dword store to hpF (local L2) + agent mirror to hpS
//  - poll: bounded sc0 dwordx2 spin on hpF; sticky per-thread fallback
//    to the round-5 agent poll on hpS if the cap trips
// All slot geometry / loop order / LDS handling byte-identical to r5.
// =========================================================
__global__ __launch_bounds__(256, 2) void lstm_scan(
    const float* __restrict__ gx,
    const float* __restrict__ W_hh,
    unsigned long long* hpF,   // [2][512] 16B slots, sc0/L2
    unsigned long long* hpS,   // [2][512] 16B slots, agent/MALL mirror
    uint*  elect,              // xcnt[8], winlock, winner
    float* out)                // [1024] = h ++ c
{
    __shared__ uint s_part[2];
    __shared__ uint hs16[2][8 * 36];   // f16-packed h, chunk c at stride 36 u32

    const int tid = threadIdx.x;

    // ---------------- election (one XCD wins) ----------------
    uint xcd;
    asm volatile("s_getreg_b32 %0, hwreg(HW_REG_XCC_ID)" : "=s"(xcd));
    xcd &= 7u;
    if (tid == 0) {
        uint* xcnt    = elect;
        uint* winlock = elect + 8;
        uint* winner  = elect + 9;
        uint slot = __hip_atomic_fetch_add(&xcnt[xcd], 1u,
                        __ATOMIC_RELAXED, __HIP_MEMORY_SCOPE_AGENT);
        if (slot == NSCAN - 1) {
            if (__hip_atomic_fetch_add(winlock, 1u,
                    __ATOMIC_ACQ_REL, __HIP_MEMORY_SCOPE_AGENT) == 0)
                __hip_atomic_store(winner, xcd + 1u,
                    __ATOMIC_RELEASE, __HIP_MEMORY_SCOPE_AGENT);
        }
        uint wn;
        while ((wn = __hip_atomic_load(winner,
                    __ATOMIC_ACQUIRE, __HIP_MEMORY_SCOPE_AGENT)) == 0)
            __builtin_amdgcn_s_sleep(2);
        s_part[0] = (wn - 1u == xcd && slot < NSCAN) ? 1u : 0u;
        s_part[1] = slot;
    }
    __syncthreads();
    if (!s_part[0]) return;
    const int w = (int)s_part[1];

    // ---------------- lane geometry (identical to round 0/5) ----------------
    const int wv = tid >> 6;       // wave id
    const int l  = tid & 63;
    const int r  = l >> 3;         // row 0..7 = gate g*2 + unit uu
    const int c  = l & 7;          // k-chunk 0..7 (64 k each)
    const int g  = r >> 1;
    const int uu = r & 1;
    const int unit  = w * 8 + wv * 2 + uu;
    const int grow  = g * 512 + unit;           // gate row in [0,2048)
    const int selu  = (l >= 32) ? 1 : 0;
    const int punit = w * 8 + wv * 2 + selu;
    const int cc  = tid >> 5;
    const int pos = tid & 31;

    // publish dword index within a [512][16B] parity plane viewed as u32[]
    const long pubw = (long)(w * 4 + wv) * 4 + selu;

    // ---------------- W_hh row segment into registers (f16) ----------------
    half2v wreg[32];
    {
        const float* wsrc = W_hh + (long)grow * HID + c * 64;
        #pragma unroll
        for (int j = 0; j < 32; ++j) {
            float2 wp = *(const float2*)&wsrc[2 * j];
            wreg[j] = pack_f16(wp.x, wp.y);
        }
    }

    float cstate = 0.0f;
    float gxcur = (c == 0) ? gx[grow] : 0.0f;
    bool slow = false;

    for (int t = 0; t < SEQ; ++t) {
        const int p = t & 1;
        const uint e16 = (uint)t & 0xFFFFu;

        // ---- acquire this thread's 2 units: ONE spin, L2-scope first ----
        uint w0, w1;
        bool got = false;
        if (!slow) {
            const unsigned long long* srcF = hpF + (long)p * 1024 + 2 * tid;
            int spins = 0;
            for (;;) {
                v2u pv;
                asm volatile("global_load_dwordx2 %0, %1, off sc0\n\t"
                             "s_waitcnt vmcnt(0)"
                             : "=v"(pv) : "v"(srcF) : "memory");
                if (((pv.x >> 16) == e16) & ((pv.y >> 16) == e16)) {
                    w0 = pv.x; w1 = pv.y; got = true; break;
                }
                if (++spins == SPIN_CAP) { slow = true; break; }
            }
        }
        if (!got) {
            const unsigned long long* srcS = hpS + (long)p * 1024 + 2 * tid;
            unsigned long long v;
            do {
                v  = __hip_atomic_load(srcS, __ATOMIC_RELAXED, __HIP_MEMORY_SCOPE_AGENT);
                w0 = (uint)v;
                w1 = (uint)(v >> 32);
            } while ((w0 >> 16) != e16 || (w1 >> 16) != e16);
        }

        // keep the gx prefetch BELOW the spin (round-0 order)
        asm volatile("" ::: "memory");

        // payload is the f16 pair -> straight into LDS
        hs16[p][cc * 36 + pos] = (w0 & 0xFFFFu) | (w1 << 16);

        // prefetch next step's gx (overlaps with barrier + compute)
        float gxn = 0.0f;
        if (c == 0 && t + 1 < SEQ) gxn = gx[(long)(t + 1) * GDIM + grow];

        __syncthreads();

        // ---- load h chunk c (64 f16 = 32 u32) ----
        uint hh[32];
        #pragma unroll
        for (int j = 0; j < 32; j += 4)
            *(v4u*)&hh[j] = *(const v4u*)&hs16[p][c * 36 + j];

        // ---- 64-deep f16 dot for row r, chunk c ----
        float acc = 0.0f;
        #pragma unroll
        for (int j = 0; j < 32; ++j)
            acc = FDOT2(wreg[j], *(half2v*)&hh[j], acc);

        // reduce across the 8 k-chunks (lane bits 0..2)
        acc += __shfl_xor(acc, 1, 64);
        acc += __shfl_xor(acc, 2, 64);
        acc += __shfl_xor(acc, 4, 64);

        const float accg = acc + gxcur;   // valid on c==0 lanes
        gxcur = gxn;

        // gather this half-wave's unit gates from the c==0 lanes
        const float gi = __shfl(accg, 8 * (0 + selu), 64);
        const float gf = __shfl(accg, 8 * (2 + selu), 64);
        const float gc = __shfl(accg, 8 * (4 + selu), 64);
        const float go = __shfl(accg, 8 * (6 + selu), 64);

        const float ig = 1.0f / (1.0f + __expf(-gi));
        const float fg = 1.0f / (1.0f + __expf(-gf));
        const float gg = 2.0f / (1.0f + __expf(-2.0f * gc)) - 1.0f;
        const float og = 1.0f / (1.0f + __expf(-go));
        cstate = fg * cstate + ig * gg;
        const float tc = 2.0f / (1.0f + __expf(-2.0f * cstate)) - 1.0f;
        const float hnew = og * tc;

        // ---- publish (lanes 0 and 32): ONE dword {epoch16 | f16(h)} ----
        if ((l & 31) == 0) {
            half2v ph = pack_f16(hnew, hnew);
            const uint hb = (*(uint*)&ph) & 0xFFFFu;
            const uint pw = (((uint)(t + 1) & 0xFFFFu) << 16) | hb;
            const long poff = (long)((t + 1) & 1) * 2048 + pubw;
            uint* dstF = (uint*)hpF + poff;
            asm volatile("global_store_dword %0, %1, off sc0"
                         :: "v"(dstF), "v"(pw) : "memory");
            __hip_atomic_store((uint*)hpS + poff, pw,
                               __ATOMIC_RELAXED, __HIP_MEMORY_SCOPE_AGENT);
            if (t == SEQ - 1) {
                out[punit]       = hnew;
                out[HID + punit] = cstate;
            }
        }
        // no trailing barrier: next iteration uses the other hs16 parity
    }
}

// =========================================================
extern "C" void kernel_launch(void* const* d_in, const int* in_sizes, int n_in,
                              void* d_out, int out_size, void* d_ws, size_t ws_size,
                              hipStream_t stream)
{
    const int*   tokens = (const int*)  d_in[0];
    const float* emb    = (const float*)d_in[1];
    const float* W_ih   = (const float*)d_in[2];
    const float* W_hh   = (const float*)d_in[3];
    const float* b_ih   = (const float*)d_in[4];
    const float* b_hh   = (const float*)d_in[5];
    float* out = (float*)d_out;

    char* ws = (char*)d_ws;
    float*              gx    = (float*)ws;
    unsigned long long* hpF   = (unsigned long long*)(ws + GX_BYTES);
    unsigned long long* hpS   = (unsigned long long*)(ws + GX_BYTES + 16384);
    uint*               elect = (uint*)(ws + GX_BYTES + 32768);
    int*                initz = (int*)(ws + GX_BYTES);

    gemm_gx<<<dim3(GDIM / 64, SEQ / 64), 256, 0, stream>>>(
        tokens, emb, W_ih, b_ih, b_hh, gx, initz);

    lstm_scan<<<dim3(GRID_SCAN), 256, 0, stream>>>(gx, W_hh, hpF, hpS, elect, out);
}

// Round 7
// 7725.527 us; speedup vs baseline: 3.1046x; 3.1046x over previous
//
#include <hip/hip_runtime.h>
#include <hip/hip_bf16.h>

#define SEQ   4096
#define HID   512
#define GDIM  2048           // 4*HID
#define NSCAN 64             // scan participants (one XCD: 32 CUs x 2 WGs)
#define GRID_SCAN 512        // oversubscribe so some XCD surely fills 64 WGs

// ---------------- workspace layout (bytes) ----------------
// [0, 33554432)        : gx  [SEQ][GDIM] f32  (32 MB)
// [+0, +16384)         : hp2 [2][512] 16B slots; slot s holds two u32 words
//                        {epoch16<<16 | f16(h_2s)} , {epoch16<<16 | f16(h_2s+1)}
// [+16384, +16424)     : election: xcnt[8], winlock, winner
#define GX_BYTES   (33554432L)
#define INIT_WORDS 4106      // (16384 + 40)/4

typedef unsigned uint;
typedef uint  v4u __attribute__((ext_vector_type(4)));
typedef _Float16 half2v __attribute__((ext_vector_type(2)));

static __device__ __forceinline__ half2v pack_f16(float a, float b) {
    return __builtin_bit_cast(half2v, __builtin_amdgcn_cvt_pkrtz(a, b));
}

#if __has_builtin(__builtin_amdgcn_fdot2)
#define FDOT2(a,b,c) __builtin_amdgcn_fdot2((a),(b),(c),false)
#else
static __device__ __forceinline__ float FDOT2(half2v a, half2v b, float c) {
    return c + (float)a.x * (float)b.x + (float)a.y * (float)b.y;
}
#endif

// =========================================================
// Kernel A: gx[t][j] = emb[tok[t]] . W_ih[j] + b_ih[j] + b_hh[j]
// (unchanged from the verified kernel)
// =========================================================
__global__ __launch_bounds__(256) void gemm_gx(
    const int*   __restrict__ tokens,
    const float* __restrict__ emb,
    const float* __restrict__ W_ih,
    const float* __restrict__ b_ih,
    const float* __restrict__ b_hh,
    float*       __restrict__ gx,
    int*         __restrict__ initzone)
{
    __shared__ float As[64][33];
    __shared__ float Bs[64][33];
    __shared__ int   tok_s[64];

    const int tid = threadIdx.x;
    const int j0  = blockIdx.x * 64;
    const int t0  = blockIdx.y * 64;

    if (blockIdx.x == 0 && blockIdx.y == 0) {
        for (int i = tid; i < INIT_WORDS; i += 256) initzone[i] = 0;
    }
    if (tid < 64) tok_s[tid] = tokens[t0 + tid];
    __syncthreads();

    const int i  = tid >> 2;
    const int ko = (tid & 3) * 8;
    const int ty = tid >> 4;
    const int tx = tid & 15;

    const long arow = (long)tok_s[i] * HID;
    const long brow = (long)(j0 + i) * HID;

    float acc[4][4] = {};

    for (int k0 = 0; k0 < HID; k0 += 32) {
        float4 a0 = *(const float4*)&emb[arow + k0 + ko];
        float4 a1 = *(const float4*)&emb[arow + k0 + ko + 4];
        float4 b0 = *(const float4*)&W_ih[brow + k0 + ko];
        float4 b1 = *(const float4*)&W_ih[brow + k0 + ko + 4];
        As[i][ko+0]=a0.x; As[i][ko+1]=a0.y; As[i][ko+2]=a0.z; As[i][ko+3]=a0.w;
        As[i][ko+4]=a1.x; As[i][ko+5]=a1.y; As[i][ko+6]=a1.z; As[i][ko+7]=a1.w;
        Bs[i][ko+0]=b0.x; Bs[i][ko+1]=b0.y; Bs[i][ko+2]=b0.z; Bs[i][ko+3]=b0.w;
        Bs[i][ko+4]=b1.x; Bs[i][ko+5]=b1.y; Bs[i][ko+6]=b1.z; Bs[i][ko+7]=b1.w;
        __syncthreads();

        #pragma unroll
        for (int kk = 0; kk < 32; ++kk) {
            float av0 = As[ty*4+0][kk], av1 = As[ty*4+1][kk];
            float av2 = As[ty*4+2][kk], av3 = As[ty*4+3][kk];
            float bv0 = Bs[tx*4+0][kk], bv1 = Bs[tx*4+1][kk];
            float bv2 = Bs[tx*4+2][kk], bv3 = Bs[tx*4+3][kk];
            acc[0][0] += av0*bv0; acc[0][1] += av0*bv1; acc[0][2] += av0*bv2; acc[0][3] += av0*bv3;
            acc[1][0] += av1*bv0; acc[1][1] += av1*bv1; acc[1][2] += av1*bv2; acc[1][3] += av1*bv3;
            acc[2][0] += av2*bv0; acc[2][1] += av2*bv1; acc[2][2] += av2*bv2; acc[2][3] += av2*bv3;
            acc[3][0] += av3*bv0; acc[3][1] += av3*bv1; acc[3][2] += av3*bv2; acc[3][3] += av3*bv3;
        }
        __syncthreads();
    }

    #pragma unroll
    for (int m = 0; m < 4; ++m) {
        const long t = t0 + ty*4 + m;
        #pragma unroll
        for (int n = 0; n < 4; ++n) {
            const int j = j0 + tx*4 + n;
            gx[t*GDIM + j] = acc[m][n] + b_ih[j] + b_hh[j];
        }
    }
}

// =========================================================
// Kernel B: EXACT round-5 kernel (single {epoch16|f16}-dword detect,
// agent-scope broadcast) with ONE change: the per-step barrier is a raw
// s_barrier preceded only by s_waitcnt lgkmcnt(0) (LDS visibility),
// NOT __syncthreads' full vmcnt(0) drain — so the gx prefetch issued
// before the barrier stays in flight across it and its HBM latency
// drains under the dot-product instead of serializing in the barrier.
// =========================================================
__global__ __launch_bounds__(256, 2) void lstm_scan(
    const float* __restrict__ gx,
    const float* __restrict__ W_hh,
    unsigned long long* hp2,   // [2][512] 16B slots
    uint*  elect,              // xcnt[8], winlock, winner
    float* out)                // [1024] = h ++ c
{
    __shared__ uint s_part[2];
    __shared__ uint hs16[2][8 * 36];   // f16-packed h, chunk c at stride 36 u32

    const int tid = threadIdx.x;

    // ---------------- election (one XCD wins) ----------------
    uint xcd;
    asm volatile("s_getreg_b32 %0, hwreg(HW_REG_XCC_ID)" : "=s"(xcd));
    xcd &= 7u;
    if (tid == 0) {
        uint* xcnt    = elect;
        uint* winlock = elect + 8;
        uint* winner  = elect + 9;
        uint slot = __hip_atomic_fetch_add(&xcnt[xcd], 1u,
                        __ATOMIC_RELAXED, __HIP_MEMORY_SCOPE_AGENT);
        if (slot == NSCAN - 1) {
            if (__hip_atomic_fetch_add(winlock, 1u,
                    __ATOMIC_ACQ_REL, __HIP_MEMORY_SCOPE_AGENT) == 0)
                __hip_atomic_store(winner, xcd + 1u,
                    __ATOMIC_RELEASE, __HIP_MEMORY_SCOPE_AGENT);
        }
        uint wn;
        while ((wn = __hip_atomic_load(winner,
                    __ATOMIC_ACQUIRE, __HIP_MEMORY_SCOPE_AGENT)) == 0)
            __builtin_amdgcn_s_sleep(2);
        s_part[0] = (wn - 1u == xcd && slot < NSCAN) ? 1u : 0u;
        s_part[1] = slot;
    }
    __syncthreads();
    if (!s_part[0]) return;
    const int w = (int)s_part[1];

    // ---------------- lane geometry (identical to round 0/5) ----------------
    const int wv = tid >> 6;       // wave id
    const int l  = tid & 63;
    const int r  = l >> 3;         // row 0..7 = gate g*2 + unit uu
    const int c  = l & 7;          // k-chunk 0..7 (64 k each)
    const int g  = r >> 1;
    const int uu = r & 1;
    const int unit  = w * 8 + wv * 2 + uu;
    const int grow  = g * 512 + unit;           // gate row in [0,2048)
    const int selu  = (l >= 32) ? 1 : 0;
    const int punit = w * 8 + wv * 2 + selu;
    const int cc  = tid >> 5;
    const int pos = tid & 31;

    // publish dword index within [2][512][16B] region viewed as u32[]
    const long pubw = (long)(w * 4 + wv) * 4 + selu;

    // ---------------- W_hh row segment into registers (f16) ----------------
    half2v wreg[32];
    {
        const float* wsrc = W_hh + (long)grow * HID + c * 64;
        #pragma unroll
        for (int j = 0; j < 32; ++j) {
            float2 wp = *(const float2*)&wsrc[2 * j];
            wreg[j] = pack_f16(wp.x, wp.y);
        }
    }

    float cstate = 0.0f;
    float gxcur = (c == 0) ? gx[grow] : 0.0f;

    for (int t = 0; t < SEQ; ++t) {
        const int p = t & 1;

        // ---- acquire this thread's 2 units: ONE dependent spin ----
        const unsigned long long* src = hp2 + (long)p * 1024 + 2 * tid;
        const uint e16 = (uint)t & 0xFFFFu;
        unsigned long long v;
        uint w0, w1;
        do {
            v  = __hip_atomic_load(src, __ATOMIC_RELAXED, __HIP_MEMORY_SCOPE_AGENT);
            w0 = (uint)v;
            w1 = (uint)(v >> 32);
        } while ((w0 >> 16) != e16 || (w1 >> 16) != e16);

        // keep the gx prefetch BELOW the spin (round-0 order)
        asm volatile("" ::: "memory");

        // payload is the f16 pair -> straight into LDS
        hs16[p][cc * 36 + pos] = (w0 & 0xFFFFu) | (w1 << 16);

        // prefetch next step's gx; stays IN FLIGHT across the raw barrier
        float gxn = 0.0f;
        if (c == 0 && t + 1 < SEQ) gxn = gx[(long)(t + 1) * GDIM + grow];

        // ---- relaxed barrier: LDS visibility only, NO vmcnt drain ----
        asm volatile("s_waitcnt lgkmcnt(0)" ::: "memory");
        __builtin_amdgcn_s_barrier();
        asm volatile("" ::: "memory");

        // ---- load h chunk c (64 f16 = 32 u32) ----
        uint hh[32];
        #pragma unroll
        for (int j = 0; j < 32; j += 4)
            *(v4u*)&hh[j] = *(const v4u*)&hs16[p][c * 36 + j];

        // ---- 64-deep f16 dot for row r, chunk c ----
        float acc = 0.0f;
        #pragma unroll
        for (int j = 0; j < 32; ++j)
            acc = FDOT2(wreg[j], *(half2v*)&hh[j], acc);

        // reduce across the 8 k-chunks (lane bits 0..2)
        acc += __shfl_xor(acc, 1, 64);
        acc += __shfl_xor(acc, 2, 64);
        acc += __shfl_xor(acc, 4, 64);

        const float accg = acc + gxcur;   // valid on c==0 lanes
        gxcur = gxn;

        // gather this half-wave's unit gates from the c==0 lanes
        const float gi = __shfl(accg, 8 * (0 + selu), 64);
        const float gf = __shfl(accg, 8 * (2 + selu), 64);
        const float gc = __shfl(accg, 8 * (4 + selu), 64);
        const float go = __shfl(accg, 8 * (6 + selu), 64);

        const float ig = 1.0f / (1.0f + __expf(-gi));
        const float fg = 1.0f / (1.0f + __expf(-gf));
        const float gg = 2.0f / (1.0f + __expf(-2.0f * gc)) - 1.0f;
        const float og = 1.0f / (1.0f + __expf(-go));
        cstate = fg * cstate + ig * gg;
        const float tc = 2.0f / (1.0f + __expf(-2.0f * cstate)) - 1.0f;
        const float hnew = og * tc;

        // ---- publish (lanes 0 and 32): ONE dword {epoch16 | f16(h)} ----
        if ((l & 31) == 0) {
            half2v ph = pack_f16(hnew, hnew);
            const uint hb = (*(uint*)&ph) & 0xFFFFu;
            const uint pw = (((uint)(t + 1) & 0xFFFFu) << 16) | hb;
            uint* dst = (uint*)hp2 + (long)((t + 1) & 1) * 2048 + pubw;
            __hip_atomic_store(dst, pw,
                               __ATOMIC_RELAXED, __HIP_MEMORY_SCOPE_AGENT);
            if (t == SEQ - 1) {
                out[punit]       = hnew;
                out[HID + punit] = cstate;
            }
        }
        // no trailing barrier: next iteration uses the other hs16 parity
    }
}

// =========================================================
extern "C" void kernel_launch(void* const* d_in, const int* in_sizes, int n_in,
                              void* d_out, int out_size, void* d_ws, size_t ws_size,
                              hipStream_t stream)
{
    const int*   tokens = (const int*)  d_in[0];
    const float* emb    = (const float*)d_in[1];
    const float* W_ih   = (const float*)d_in[2];
    const float* W_hh   = (const float*)d_in[3];
    const float* b_ih   = (const float*)d_in[4];
    const float* b_hh   = (const float*)d_in[5];
    float* out = (float*)d_out;

    char* ws = (char*)d_ws;
    float*              gx    = (float*)ws;
    unsigned long long* hp2   = (unsigned long long*)(ws + GX_BYTES);
    uint*               elect = (uint*)(ws + GX_BYTES + 16384);
    int*                initz = (int*)(ws + GX_BYTES);

    gemm_gx<<<dim3(GDIM / 64, SEQ / 64), 256, 0, stream>>>(
        tokens, emb, W_ih, b_ih, b_hh, gx, initz);

    lstm_scan<<<dim3(GRID_SCAN), 256, 0, stream>>>(gx, W_hh, hp2, elect, out);
}